// Round 3
// baseline (845.529 us; speedup 1.0000x reference)
//
#include <hip/hip_runtime.h>

#define HD   128          // hidden dim
#define SEQ  15
#define BN   16           // batch rows per block
#define LDH  136          // hb row stride (bf16 elems): 272 B, 2-way-max bank alias
#define KT   4            // K tiles of 32 (h only, K=128)
#define NTHR 512          // 8 waves
#define LXB  68           // xbuf row stride (f16 elems): 136 B -> conflict-free row spread

typedef __bf16 bf16x8 __attribute__((ext_vector_type(8)));
typedef unsigned short us8 __attribute__((ext_vector_type(8)));
typedef float f32x4 __attribute__((ext_vector_type(4)));
typedef _Float16 h2 __attribute__((ext_vector_type(2)));

__device__ __forceinline__ unsigned short f2bf(float f) {
  unsigned int u = __builtin_bit_cast(unsigned int, f);
  u += 0x7fffu + ((u >> 16) & 1u);          // RNE
  return (unsigned short)(u >> 16);
}
__device__ __forceinline__ float bfl(unsigned int u) { return __builtin_bit_cast(float, u << 16); }
__device__ __forceinline__ float bfh(unsigned int u) { return __builtin_bit_cast(float, u & 0xffff0000u); }

__device__ __forceinline__ float dot2f(h2 a, h2 b, float c) {
#if __has_builtin(__builtin_amdgcn_fdot2)
  return __builtin_amdgcn_fdot2(a, b, c, false);
#else
  return c + (float)a[0] * (float)b[0] + (float)a[1] * (float)b[1];
#endif
}

// Build per-wave B-fragments (K=128) + f16 Wih pairs + bias (decoder: feedback fold).
static __device__ __forceinline__ void load_weights(
    const float* __restrict__ Wih, const float* __restrict__ Whh,
    const float* __restrict__ bih, const float* __restrict__ bhh,
    const float* __restrict__ oW,  const float* __restrict__ ob,
    bool fold, int wv, int l15, int lk,
    bf16x8 (&bw)[4][KT], h2 (&wih)[4][2], float (&bb)[4])
{
  #pragma unroll
  for (int g = 0; g < 4; ++g) {
    const int gc = g * HD + wv * 16 + l15;
    float wi[4];
    #pragma unroll
    for (int d = 0; d < 4; ++d) wi[d] = Wih[gc * 4 + d];
    float b = bih[gc] + bhh[gc];
    if (fold) {
      #pragma unroll
      for (int d = 0; d < 4; ++d) b += ob[d] * wi[d];
    }
    bb[g] = b;
    wih[g][0] = h2{(_Float16)wi[0], (_Float16)wi[1]};
    wih[g][1] = h2{(_Float16)wi[2], (_Float16)wi[3]};
    #pragma unroll
    for (int kt = 0; kt < KT; ++kt) {
      const int k0 = kt * 32 + lk * 8;
      const float4* p = (const float4*)&Whh[(size_t)gc * HD + k0];
      const float4 u0 = p[0], u1 = p[1];
      float v[8] = {u0.x, u0.y, u0.z, u0.w, u1.x, u1.y, u1.z, u1.w};
      if (fold) {           // W' = Whh^T + out_W^T @ Wih^T
        #pragma unroll
        for (int j = 0; j < 8; ++j) {
          float s = v[j];
          #pragma unroll
          for (int d = 0; d < 4; ++d) s += wi[d] * oW[d * HD + k0 + j];
          v[j] = s;
        }
      }
      us8 u;
      #pragma unroll
      for (int j = 0; j < 8; ++j) u[j] = f2bf(v[j]);
      bw[g][kt] = __builtin_bit_cast(bf16x8, u);
    }
  }
}

__global__ __launch_bounds__(NTHR, 4) void lstm_encdec_kernel(
    const float* __restrict__ x,
    const float* __restrict__ eWih, const float* __restrict__ eWhh,
    const float* __restrict__ ebih, const float* __restrict__ ebhh,
    const float* __restrict__ dWih, const float* __restrict__ dWhh,
    const float* __restrict__ dbih, const float* __restrict__ dbhh,
    const float* __restrict__ oW,  const float* __restrict__ ob,
    float* __restrict__ out)
{
  const int tid  = (int)threadIdx.x;
  const int wv   = tid >> 6;
  const int l15  = tid & 15;
  const int lk   = (tid & 63) >> 4;
  const int b0   = (int)blockIdx.x * BN;
  // proj split: value (pb,pd) by 8 threads (pq = K-eighth)
  const int pv = tid >> 3, pb = pv >> 2, pd = pv & 3, pq = tid & 7;

  __shared__ alignas(16) unsigned short hb[2][BN][LDH];  // h, bf16, double-buffered
  __shared__ alignas(16) unsigned short xbuf[BN][LXB];   // x as f16 bits; cols 64..67 = dec corr
  __shared__ alignas(16) float obuf[BN][64];             // staged predictions
  __shared__ float ow_l[4][134];
  __shared__ float ob_l[4];

  bf16x8 bw[4][KT];
  h2     wih[4][2];
  float  bb[4];
  f32x4  cst = {0.f, 0.f, 0.f, 0.f};
  f32x4  hst = {0.f, 0.f, 0.f, 0.f};

  for (int i = tid; i < 2 * BN * LDH; i += NTHR) ((unsigned short*)hb)[i] = 0;

  if (tid < 240) {          // stage all x -> f16 LDS (coalesced float4)
    const int b = tid / 15, c = tid % 15;
    const float4 xv = *(const float4*)&x[(size_t)(b0 + b) * 60 + c * 4];
    const h2 lo = {(_Float16)xv.x, (_Float16)xv.y};
    const h2 hi = {(_Float16)xv.z, (_Float16)xv.w};
    *(uint2*)&xbuf[b][c * 4] =
        uint2{__builtin_bit_cast(unsigned, lo), __builtin_bit_cast(unsigned, hi)};
  }

  load_weights(eWih, eWhh, ebih, ebhh, oW, ob, false, wv, l15, lk, bw, wih, bb);
  __syncthreads();

  // ================= encoder =================
  int p = 0;
  for (int t = 0; t < SEQ; ++t) {
    f32x4 acc[4];
    #pragma unroll
    for (int g = 0; g < 4; ++g)
      #pragma unroll
      for (int j = 0; j < 4; ++j) acc[g][j] = bb[g];
    #pragma unroll
    for (int j = 0; j < 4; ++j) {          // x_t @ Wih^T via packed f16 dot2
      const uint2 xv = *(const uint2*)&xbuf[lk * 4 + j][t * 4];
      const h2 xlo = __builtin_bit_cast(h2, xv.x);
      const h2 xhi = __builtin_bit_cast(h2, xv.y);
      #pragma unroll
      for (int g = 0; g < 4; ++g)
        acc[g][j] = dot2f(wih[g][1], xhi, dot2f(wih[g][0], xlo, acc[g][j]));
    }
    #pragma unroll
    for (int kt = 0; kt < KT; ++kt) {
      const bf16x8 a = __builtin_bit_cast(bf16x8,
          *(const uint4*)&hb[p][l15][kt * 32 + lk * 8]);
      #pragma unroll
      for (int g = 0; g < 4; ++g)
        acc[g] = __builtin_amdgcn_mfma_f32_16x16x32_bf16(a, bw[g][kt], acc[g], 0, 0, 0);
    }
    #pragma unroll
    for (int j = 0; j < 4; ++j) {          // activations: 5 exp + 3 rcp
      const float ei = __expf(-acc[0][j]);
      const float ef = __expf(-acc[1][j]);
      const float eg = __expf(2.f * acc[2][j]);
      const float eo = __expf(-acc[3][j]);
      const float c  = cst[j] * __builtin_amdgcn_rcpf(1.f + ef)
                     + (eg - 1.f) * __builtin_amdgcn_rcpf((1.f + ei) * (eg + 1.f));
      cst[j] = c;
      const float ec = __expf(2.f * c);
      hst[j] = (ec - 1.f) * __builtin_amdgcn_rcpf((1.f + eo) * (ec + 1.f));
    }
    #pragma unroll
    for (int j = 0; j < 4; ++j)
      hb[p ^ 1][lk * 4 + j][wv * 16 + l15] = f2bf(hst[j]);
    __syncthreads();
    p ^= 1;
  }

  // ================= decoder setup =================
  cst = hst;                                // dec c0 = h_enc (exact f32)
  load_weights(dWih, dWhh, dbih, dbhh, oW, ob, true, wv, l15, lk, bw, wih, bb);
  for (int i = tid; i < 4 * HD; i += NTHR) ow_l[i >> 7][i & 127] = oW[i];
  if (tid < 4) ob_l[tid] = ob[tid];
  __syncthreads();

  {                                         // step-0 correction: x-slot = x14 - proj(h_enc)
    float s = 0.f;
    #pragma unroll
    for (int c = 0; c < 2; ++c) {
      const int k = pq * 16 + ((c + pq) & 1) * 8;
      const uint4 hv = *(const uint4*)&hb[p][pb][k];
      const float* w = &ow_l[pd][k];
      s += bfl(hv.x) * w[0] + bfh(hv.x) * w[1]
         + bfl(hv.y) * w[2] + bfh(hv.y) * w[3]
         + bfl(hv.z) * w[4] + bfh(hv.z) * w[5]
         + bfl(hv.w) * w[6] + bfh(hv.w) * w[7];
    }
    s += __shfl_xor(s, 1); s += __shfl_xor(s, 2); s += __shfl_xor(s, 4);
    s += ob_l[pd];
    if (pq == 0) {
      const _Float16 x14 = __builtin_bit_cast(_Float16, xbuf[pb][56 + pd]);
      xbuf[pb][64 + pd] = __builtin_bit_cast(unsigned short, (_Float16)((float)x14 - s));
    }
  }
  __syncthreads();

  // ================= decoder (folded feedback) =================
  for (int t = 0; t < SEQ; ++t) {
    f32x4 acc[4];
    #pragma unroll
    for (int g = 0; g < 4; ++g)
      #pragma unroll
      for (int j = 0; j < 4; ++j) acc[g][j] = bb[g];
    if (t == 0) {
      #pragma unroll
      for (int j = 0; j < 4; ++j) {
        const uint2 xv = *(const uint2*)&xbuf[lk * 4 + j][64];
        const h2 xlo = __builtin_bit_cast(h2, xv.x);
        const h2 xhi = __builtin_bit_cast(h2, xv.y);
        #pragma unroll
        for (int g = 0; g < 4; ++g)
          acc[g][j] = dot2f(wih[g][1], xhi, dot2f(wih[g][0], xlo, acc[g][j]));
      }
    }
    #pragma unroll
    for (int kt = 0; kt < KT; ++kt) {
      const bf16x8 a = __builtin_bit_cast(bf16x8,
          *(const uint4*)&hb[p][l15][kt * 32 + lk * 8]);
      #pragma unroll
      for (int g = 0; g < 4; ++g)
        acc[g] = __builtin_amdgcn_mfma_f32_16x16x32_bf16(a, bw[g][kt], acc[g], 0, 0, 0);
    }
    if (t > 0) {                            // output t-1 = proj(h_t); overlaps MFMA latency
      float s = 0.f;
      #pragma unroll
      for (int c = 0; c < 2; ++c) {
        const int k = pq * 16 + ((c + pq) & 1) * 8;
        const uint4 hv = *(const uint4*)&hb[p][pb][k];
        const float* w = &ow_l[pd][k];
        s += bfl(hv.x) * w[0] + bfh(hv.x) * w[1]
           + bfl(hv.y) * w[2] + bfh(hv.y) * w[3]
           + bfl(hv.z) * w[4] + bfh(hv.z) * w[5]
           + bfl(hv.w) * w[6] + bfh(hv.w) * w[7];
      }
      s += __shfl_xor(s, 1); s += __shfl_xor(s, 2); s += __shfl_xor(s, 4);
      if (pq == 0) obuf[pb][(t - 1) * 4 + pd] = s + ob_l[pd];
    }
    #pragma unroll
    for (int j = 0; j < 4; ++j) {
      const float ei = __expf(-acc[0][j]);
      const float ef = __expf(-acc[1][j]);
      const float eg = __expf(2.f * acc[2][j]);
      const float eo = __expf(-acc[3][j]);
      const float c  = cst[j] * __builtin_amdgcn_rcpf(1.f + ef)
                     + (eg - 1.f) * __builtin_amdgcn_rcpf((1.f + ei) * (eg + 1.f));
      cst[j] = c;
      const float ec = __expf(2.f * c);
      hst[j] = (ec - 1.f) * __builtin_amdgcn_rcpf((1.f + eo) * (ec + 1.f));
    }
    #pragma unroll
    for (int j = 0; j < 4; ++j)
      hb[p ^ 1][lk * 4 + j][wv * 16 + l15] = f2bf(hst[j]);
    __syncthreads();
    p ^= 1;
  }
  {                                         // final output from h_15
    float s = 0.f;
    #pragma unroll
    for (int c = 0; c < 2; ++c) {
      const int k = pq * 16 + ((c + pq) & 1) * 8;
      const uint4 hv = *(const uint4*)&hb[p][pb][k];
      const float* w = &ow_l[pd][k];
      s += bfl(hv.x) * w[0] + bfh(hv.x) * w[1]
         + bfl(hv.y) * w[2] + bfh(hv.y) * w[3]
         + bfl(hv.z) * w[4] + bfh(hv.z) * w[5]
         + bfl(hv.w) * w[6] + bfh(hv.w) * w[7];
    }
    s += __shfl_xor(s, 1); s += __shfl_xor(s, 2); s += __shfl_xor(s, 4);
    if (pq == 0) obuf[pb][56 + pd] = s + ob_l[pd];
  }
  __syncthreads();

  if (tid < 240) {                          // coalesced dump
    const int b = tid / 15, c = tid % 15;
    const float4 v = *(const float4*)&obuf[b][c * 4];
    *(float4*)&out[(size_t)(b0 + b) * 60 + c * 4] = v;
  }
}

extern "C" void kernel_launch(void* const* d_in, const int* in_sizes, int n_in,
                              void* d_out, int out_size, void* d_ws, size_t ws_size,
                              hipStream_t stream) {
  const float* x    = (const float*)d_in[0];
  const float* eWih = (const float*)d_in[1];
  const float* eWhh = (const float*)d_in[2];
  const float* ebih = (const float*)d_in[3];
  const float* ebhh = (const float*)d_in[4];
  const float* dWih = (const float*)d_in[5];
  const float* dWhh = (const float*)d_in[6];
  const float* dbih = (const float*)d_in[7];
  const float* dbhh = (const float*)d_in[8];
  const float* oW   = (const float*)d_in[9];
  const float* ob   = (const float*)d_in[10];

  const int batch = in_sizes[0] / (SEQ * 4);   // 32768
  dim3 grid(batch / BN), block(NTHR);
  lstm_encdec_kernel<<<grid, block, 0, stream>>>(
      x, eWih, eWhh, ebih, ebhh, dWih, dWhh, dbih, dbhh, oW, ob, (float*)d_out);
}

// Round 4
// 552.378 us; speedup vs baseline: 1.5307x; 1.5307x over previous
//
#include <hip/hip_runtime.h>

#define HD   128          // hidden dim
#define SEQ  15
#define BN   16           // batch rows per block
#define LDH  136          // hb row stride (bf16 elems): 272 B, 2-way-max bank alias
#define KT   4            // K tiles of 32 (h only, K=128)
#define NTHR 512          // 8 waves

typedef __bf16 bf16x8 __attribute__((ext_vector_type(8)));
typedef unsigned short us8 __attribute__((ext_vector_type(8)));
typedef float f32x4 __attribute__((ext_vector_type(4)));
typedef _Float16 h2 __attribute__((ext_vector_type(2)));

__device__ __forceinline__ unsigned short f2bf(float f) {
  unsigned int u = __builtin_bit_cast(unsigned int, f);
  u += 0x7fffu + ((u >> 16) & 1u);          // RNE
  return (unsigned short)(u >> 16);
}
__device__ __forceinline__ float bfl(unsigned int u) { return __builtin_bit_cast(float, u << 16); }
__device__ __forceinline__ float bfh(unsigned int u) { return __builtin_bit_cast(float, u & 0xffff0000u); }

__device__ __forceinline__ float dot2f(h2 a, h2 b, float c) {
#if __has_builtin(__builtin_amdgcn_fdot2)
  return __builtin_amdgcn_fdot2(a, b, c, false);
#else
  return c + (float)a[0] * (float)b[0] + (float)a[1] * (float)b[1];
#endif
}

// Build per-wave B-fragments (K=128) + f16 Wih pairs + bias (decoder: feedback fold).
static __device__ __forceinline__ void load_weights(
    const float* __restrict__ Wih, const float* __restrict__ Whh,
    const float* __restrict__ bih, const float* __restrict__ bhh,
    const float* __restrict__ oW,  const float* __restrict__ ob,
    bool fold, int wv, int l15, int lk,
    bf16x8 (&bw)[4][KT], h2 (&wih)[4][2], float (&bb)[4])
{
  #pragma unroll
  for (int g = 0; g < 4; ++g) {
    const int gc = g * HD + wv * 16 + l15;
    float wi[4];
    #pragma unroll
    for (int d = 0; d < 4; ++d) wi[d] = Wih[gc * 4 + d];
    float b = bih[gc] + bhh[gc];
    if (fold) {
      #pragma unroll
      for (int d = 0; d < 4; ++d) b += ob[d] * wi[d];
    }
    bb[g] = b;
    wih[g][0] = h2{(_Float16)wi[0], (_Float16)wi[1]};
    wih[g][1] = h2{(_Float16)wi[2], (_Float16)wi[3]};
    #pragma unroll
    for (int kt = 0; kt < KT; ++kt) {
      const int k0 = kt * 32 + lk * 8;
      const float4* p = (const float4*)&Whh[(size_t)gc * HD + k0];
      const float4 u0 = p[0], u1 = p[1];
      float v[8] = {u0.x, u0.y, u0.z, u0.w, u1.x, u1.y, u1.z, u1.w};
      if (fold) {           // W' = Whh^T + out_W^T @ Wih^T
        #pragma unroll
        for (int j = 0; j < 8; ++j) {
          float s = v[j];
          #pragma unroll
          for (int d = 0; d < 4; ++d) s += wi[d] * oW[d * HD + k0 + j];
          v[j] = s;
        }
      }
      us8 u;
      #pragma unroll
      for (int j = 0; j < 8; ++j) u[j] = f2bf(v[j]);
      bw[g][kt] = __builtin_bit_cast(bf16x8, u);
    }
  }
}

__global__ __launch_bounds__(NTHR, 2) void lstm_encdec_kernel(
    const float* __restrict__ x,
    const float* __restrict__ eWih, const float* __restrict__ eWhh,
    const float* __restrict__ ebih, const float* __restrict__ ebhh,
    const float* __restrict__ dWih, const float* __restrict__ dWhh,
    const float* __restrict__ dbih, const float* __restrict__ dbhh,
    const float* __restrict__ oW,  const float* __restrict__ ob,
    float* __restrict__ out)
{
  const int tid  = (int)threadIdx.x;
  const int wv   = tid >> 6;
  const int l15  = tid & 15;
  const int lk   = (tid & 63) >> 4;
  const int b0   = (int)blockIdx.x * BN;
  // proj split: value (pb,pd) by 8 threads (pq = K-eighth)
  const int pv = tid >> 3, pb = pv >> 2, pd = pv & 3, pq = tid & 7;

  __shared__ alignas(16) unsigned short hb[2][BN][LDH];  // h, bf16, double-buffered
  __shared__ alignas(16) unsigned short xbuf[BN][68];    // x as f16 bits; cols 64..67 = dec corr
  __shared__ alignas(16) float obuf[BN][64];             // staged predictions
  __shared__ float ow_l[4][134];
  __shared__ float ob_l[4];

  bf16x8 bw[4][KT];
  h2     wih[4][2];
  float  bb[4];
  f32x4  cst = {0.f, 0.f, 0.f, 0.f};
  f32x4  hst = {0.f, 0.f, 0.f, 0.f};

  for (int i = tid; i < 2 * BN * LDH; i += NTHR) ((unsigned short*)hb)[i] = 0;

  if (tid < 240) {          // stage all x -> f16 LDS (coalesced float4)
    const int b = tid / 15, c = tid % 15;
    const float4 xv = *(const float4*)&x[(size_t)(b0 + b) * 60 + c * 4];
    const h2 lo = {(_Float16)xv.x, (_Float16)xv.y};
    const h2 hi = {(_Float16)xv.z, (_Float16)xv.w};
    *(uint2*)&xbuf[b][c * 4] =
        uint2{__builtin_bit_cast(unsigned, lo), __builtin_bit_cast(unsigned, hi)};
  }

  load_weights(eWih, eWhh, ebih, ebhh, oW, ob, false, wv, l15, lk, bw, wih, bb);
  __syncthreads();

  // ================= encoder =================
  int p = 0;
  #pragma unroll 1
  for (int t = 0; t < SEQ; ++t) {
    f32x4 acc[4];
    #pragma unroll
    for (int g = 0; g < 4; ++g)
      #pragma unroll
      for (int j = 0; j < 4; ++j) acc[g][j] = bb[g];
    #pragma unroll
    for (int j = 0; j < 4; ++j) {          // x_t @ Wih^T via packed f16 dot2
      const uint2 xv = *(const uint2*)&xbuf[lk * 4 + j][t * 4];
      const h2 xlo = __builtin_bit_cast(h2, xv.x);
      const h2 xhi = __builtin_bit_cast(h2, xv.y);
      #pragma unroll
      for (int g = 0; g < 4; ++g)
        acc[g][j] = dot2f(wih[g][1], xhi, dot2f(wih[g][0], xlo, acc[g][j]));
    }
    #pragma unroll
    for (int kt = 0; kt < KT; ++kt) {
      const bf16x8 a = __builtin_bit_cast(bf16x8,
          *(const uint4*)&hb[p][l15][kt * 32 + lk * 8]);
      #pragma unroll
      for (int g = 0; g < 4; ++g)
        acc[g] = __builtin_amdgcn_mfma_f32_16x16x32_bf16(a, bw[g][kt], acc[g], 0, 0, 0);
    }
    #pragma unroll
    for (int j = 0; j < 4; ++j) {          // activations: 5 exp + 3 rcp
      const float ei = __expf(-acc[0][j]);
      const float ef = __expf(-acc[1][j]);
      const float eg = __expf(2.f * acc[2][j]);
      const float eo = __expf(-acc[3][j]);
      const float c  = cst[j] * __builtin_amdgcn_rcpf(1.f + ef)
                     + (eg - 1.f) * __builtin_amdgcn_rcpf((1.f + ei) * (eg + 1.f));
      cst[j] = c;
      const float ec = __expf(2.f * c);
      hst[j] = (ec - 1.f) * __builtin_amdgcn_rcpf((1.f + eo) * (ec + 1.f));
    }
    #pragma unroll
    for (int j = 0; j < 4; ++j)
      hb[p ^ 1][lk * 4 + j][wv * 16 + l15] = f2bf(hst[j]);
    __syncthreads();
    p ^= 1;
  }

  // ================= decoder setup =================
  cst = hst;                                // dec c0 = h_enc (exact f32)
  load_weights(dWih, dWhh, dbih, dbhh, oW, ob, true, wv, l15, lk, bw, wih, bb);
  for (int i = tid; i < 4 * HD; i += NTHR) ow_l[i >> 7][i & 127] = oW[i];
  if (tid < 4) ob_l[tid] = ob[tid];
  __syncthreads();

  {                                         // step-0 correction: x-slot = x14 - proj(h_enc)
    float s = 0.f;
    #pragma unroll
    for (int c = 0; c < 2; ++c) {
      const int k = pq * 16 + ((c + pq) & 1) * 8;
      const uint4 hv = *(const uint4*)&hb[p][pb][k];
      const float* w = &ow_l[pd][k];
      s += bfl(hv.x) * w[0] + bfh(hv.x) * w[1]
         + bfl(hv.y) * w[2] + bfh(hv.y) * w[3]
         + bfl(hv.z) * w[4] + bfh(hv.z) * w[5]
         + bfl(hv.w) * w[6] + bfh(hv.w) * w[7];
    }
    s += __shfl_xor(s, 1); s += __shfl_xor(s, 2); s += __shfl_xor(s, 4);
    s += ob_l[pd];
    if (pq == 0) {
      const _Float16 x14 = __builtin_bit_cast(_Float16, xbuf[pb][56 + pd]);
      xbuf[pb][64 + pd] = __builtin_bit_cast(unsigned short, (_Float16)((float)x14 - s));
    }
  }
  __syncthreads();

  // ================= decoder (folded feedback) =================
  #pragma unroll 1
  for (int t = 0; t < SEQ; ++t) {
    f32x4 acc[4];
    #pragma unroll
    for (int g = 0; g < 4; ++g)
      #pragma unroll
      for (int j = 0; j < 4; ++j) acc[g][j] = bb[g];
    if (t == 0) {
      #pragma unroll
      for (int j = 0; j < 4; ++j) {
        const uint2 xv = *(const uint2*)&xbuf[lk * 4 + j][64];
        const h2 xlo = __builtin_bit_cast(h2, xv.x);
        const h2 xhi = __builtin_bit_cast(h2, xv.y);
        #pragma unroll
        for (int g = 0; g < 4; ++g)
          acc[g][j] = dot2f(wih[g][1], xhi, dot2f(wih[g][0], xlo, acc[g][j]));
      }
    }
    #pragma unroll
    for (int kt = 0; kt < KT; ++kt) {
      const bf16x8 a = __builtin_bit_cast(bf16x8,
          *(const uint4*)&hb[p][l15][kt * 32 + lk * 8]);
      #pragma unroll
      for (int g = 0; g < 4; ++g)
        acc[g] = __builtin_amdgcn_mfma_f32_16x16x32_bf16(a, bw[g][kt], acc[g], 0, 0, 0);
    }
    if (t > 0) {                            // output t-1 = proj(h_t); overlaps MFMA latency
      float s = 0.f;
      #pragma unroll
      for (int c = 0; c < 2; ++c) {
        const int k = pq * 16 + ((c + pq) & 1) * 8;
        const uint4 hv = *(const uint4*)&hb[p][pb][k];
        const float* w = &ow_l[pd][k];
        s += bfl(hv.x) * w[0] + bfh(hv.x) * w[1]
           + bfl(hv.y) * w[2] + bfh(hv.y) * w[3]
           + bfl(hv.z) * w[4] + bfh(hv.z) * w[5]
           + bfl(hv.w) * w[6] + bfh(hv.w) * w[7];
      }
      s += __shfl_xor(s, 1); s += __shfl_xor(s, 2); s += __shfl_xor(s, 4);
      if (pq == 0) obuf[pb][(t - 1) * 4 + pd] = s + ob_l[pd];
    }
    #pragma unroll
    for (int j = 0; j < 4; ++j) {
      const float ei = __expf(-acc[0][j]);
      const float ef = __expf(-acc[1][j]);
      const float eg = __expf(2.f * acc[2][j]);
      const float eo = __expf(-acc[3][j]);
      const float c  = cst[j] * __builtin_amdgcn_rcpf(1.f + ef)
                     + (eg - 1.f) * __builtin_amdgcn_rcpf((1.f + ei) * (eg + 1.f));
      cst[j] = c;
      const float ec = __expf(2.f * c);
      hst[j] = (ec - 1.f) * __builtin_amdgcn_rcpf((1.f + eo) * (ec + 1.f));
    }
    #pragma unroll
    for (int j = 0; j < 4; ++j)
      hb[p ^ 1][lk * 4 + j][wv * 16 + l15] = f2bf(hst[j]);
    __syncthreads();
    p ^= 1;
  }
  {                                         // final output from h_15
    float s = 0.f;
    #pragma unroll
    for (int c = 0; c < 2; ++c) {
      const int k = pq * 16 + ((c + pq) & 1) * 8;
      const uint4 hv = *(const uint4*)&hb[p][pb][k];
      const float* w = &ow_l[pd][k];
      s += bfl(hv.x) * w[0] + bfh(hv.x) * w[1]
         + bfl(hv.y) * w[2] + bfh(hv.y) * w[3]
         + bfl(hv.z) * w[4] + bfh(hv.z) * w[5]
         + bfl(hv.w) * w[6] + bfh(hv.w) * w[7];
    }
    s += __shfl_xor(s, 1); s += __shfl_xor(s, 2); s += __shfl_xor(s, 4);
    if (pq == 0) obuf[pb][56 + pd] = s + ob_l[pd];
  }
  __syncthreads();

  if (tid < 240) {                          // coalesced dump
    const int b = tid / 15, c = tid % 15;
    const float4 v = *(const float4*)&obuf[b][c * 4];
    *(float4*)&out[(size_t)(b0 + b) * 60 + c * 4] = v;
  }
}

extern "C" void kernel_launch(void* const* d_in, const int* in_sizes, int n_in,
                              void* d_out, int out_size, void* d_ws, size_t ws_size,
                              hipStream_t stream) {
  const float* x    = (const float*)d_in[0];
  const float* eWih = (const float*)d_in[1];
  const float* eWhh = (const float*)d_in[2];
  const float* ebih = (const float*)d_in[3];
  const float* ebhh = (const float*)d_in[4];
  const float* dWih = (const float*)d_in[5];
  const float* dWhh = (const float*)d_in[6];
  const float* dbih = (const float*)d_in[7];
  const float* dbhh = (const float*)d_in[8];
  const float* oW   = (const float*)d_in[9];
  const float* ob   = (const float*)d_in[10];

  const int batch = in_sizes[0] / (SEQ * 4);   // 32768
  dim3 grid(batch / BN), block(NTHR);
  lstm_encdec_kernel<<<grid, block, 0, stream>>>(
      x, eWih, eWhh, ebih, ebhh, dWih, dWhh, dbih, dbhh, oW, ob, (float*)d_out);
}

// Round 5
// 403.297 us; speedup vs baseline: 2.0965x; 1.3697x over previous
//
#include <hip/hip_runtime.h>

#define HD   128          // hidden dim
#define SEQ  15
#define BN   64           // batch rows per block (4 tiles of 16 per wave)
#define LDH  168          // hb row stride in shorts (336 B)
#define KT   5            // K=160: h(0..127) | x(128..131) | bias-ones(132..133) | pad
#define NTHR 512          // 8 waves
#define LOB  68           // obuf row stride in floats

typedef __bf16 bf16x8 __attribute__((ext_vector_type(8)));
typedef unsigned short us8 __attribute__((ext_vector_type(8)));
typedef float f32x4 __attribute__((ext_vector_type(4)));

__device__ __forceinline__ unsigned short f2bf(float f) {
  unsigned int u = __builtin_bit_cast(unsigned int, f);
  u += 0x7fffu + ((u >> 16) & 1u);          // RNE
  return (unsigned short)(u >> 16);
}
__device__ __forceinline__ float bfl(unsigned int u) { return __builtin_bit_cast(float, u << 16); }
__device__ __forceinline__ float bfh(unsigned int u) { return __builtin_bit_cast(float, u & 0xffff0000u); }

// B-fragments for B[k][gate-col]: rows 0..127 = Whh^T (+fold), 128..131 = Wih^T,
// 132/133 = bias split hi/lo (A provides 1.0 in those channels), rest zero.
static __device__ __forceinline__ void load_weights(
    const float* __restrict__ Wih, const float* __restrict__ Whh,
    const float* __restrict__ bih, const float* __restrict__ bhh,
    const float* __restrict__ oW,  const float* __restrict__ ob,
    bool fold, int wv, int l15, int lk, bf16x8 (&bw)[4][KT])
{
  #pragma unroll
  for (int g = 0; g < 4; ++g) {
    const int gc = g * HD + wv * 16 + l15;
    float wi[4];
    #pragma unroll
    for (int d = 0; d < 4; ++d) wi[d] = Wih[gc * 4 + d];
    float bb = bih[gc] + bhh[gc];
    if (fold) {
      #pragma unroll
      for (int d = 0; d < 4; ++d) bb += ob[d] * wi[d];
    }
    #pragma unroll
    for (int kt = 0; kt < KT - 1; ++kt) {
      const int k0 = kt * 32 + lk * 8;
      const float4* p = (const float4*)&Whh[(size_t)gc * HD + k0];
      const float4 u0 = p[0], u1 = p[1];
      float v[8] = {u0.x, u0.y, u0.z, u0.w, u1.x, u1.y, u1.z, u1.w};
      if (fold) {           // W' = Whh^T + out_W^T @ Wih^T (decoder feedback fold)
        #pragma unroll
        for (int j = 0; j < 8; ++j) {
          float s = v[j];
          #pragma unroll
          for (int d = 0; d < 4; ++d) s += wi[d] * oW[d * HD + k0 + j];
          v[j] = s;
        }
      }
      us8 u;
      #pragma unroll
      for (int j = 0; j < 8; ++j) u[j] = f2bf(v[j]);
      bw[g][kt] = __builtin_bit_cast(bf16x8, u);
    }
    us8 u4 = {0, 0, 0, 0, 0, 0, 0, 0};
    if (lk == 0) {          // rows 128..135 live in lk==0's fragment
      #pragma unroll
      for (int j = 0; j < 4; ++j) u4[j] = f2bf(wi[j]);
      const unsigned short bh = f2bf(bb);
      u4[4] = bh;
      u4[5] = f2bf(bb - bfl((unsigned)bh));
    }
    bw[g][KT - 1] = __builtin_bit_cast(bf16x8, u4);
  }
}

__global__ __launch_bounds__(NTHR, 1) void lstm_encdec_kernel(
    const float* __restrict__ x,
    const float* __restrict__ eWih, const float* __restrict__ eWhh,
    const float* __restrict__ ebih, const float* __restrict__ ebhh,
    const float* __restrict__ dWih, const float* __restrict__ dWhh,
    const float* __restrict__ dbih, const float* __restrict__ dbhh,
    const float* __restrict__ oW,  const float* __restrict__ ob,
    float* __restrict__ out)
{
  const int tid  = (int)threadIdx.x;
  const int wv   = tid >> 6;
  const int l15  = tid & 15;
  const int lk   = (tid & 63) >> 4;
  const int b0   = (int)blockIdx.x * BN;
  // proj split: value (pb,pd) by 2 threads (pq = K-half)
  const int pv = tid >> 1, pb = pv >> 2, pd = pv & 3, pq = tid & 1;

  __shared__ alignas(16) unsigned short hb[2][BN][LDH];  // h bf16, double-buffered
  __shared__ alignas(16) float obuf[BN][LOB];            // staged predictions
  __shared__ float ow_l[4][134];
  __shared__ float ob_l[4];

  bf16x8 bw[4][KT];
  f32x4  cst[4], hst[4];
  #pragma unroll
  for (int m = 0; m < 4; ++m)
    #pragma unroll
    for (int j = 0; j < 4; ++j) { cst[m][j] = 0.f; hst[m][j] = 0.f; }

  // zero both h buffers; plant bias-channel 1.0s (shorts 132/133 = uint 66 of each 84-uint row)
  for (int i = tid; i < 2 * BN * (LDH / 2); i += NTHR)
    ((unsigned int*)hb)[i] = ((i % (LDH / 2)) == 66) ? 0x3F803F80u : 0u;

  load_weights(eWih, eWhh, ebih, ebhh, oW, ob, false, wv, l15, lk, bw);
  __syncthreads();
  if (tid < BN) {           // stage x_0
    const float4 xv = *(const float4*)&x[(size_t)(b0 + tid) * 60];
    *(unsigned int*)&hb[0][tid][128]     = (unsigned)f2bf(xv.x) | ((unsigned)f2bf(xv.y) << 16);
    *(unsigned int*)&hb[0][tid][128 + 2] = (unsigned)f2bf(xv.z) | ((unsigned)f2bf(xv.w) << 16);
  }
  __syncthreads();

  // ================= encoder =================
  int p = 0;
  #pragma unroll 1
  for (int t = 0; t < SEQ; ++t) {
    #pragma unroll
    for (int m = 0; m < 4; ++m) {
      f32x4 acc[4];
      {
        const bf16x8 a = __builtin_bit_cast(bf16x8,
            *(const uint4*)&hb[p][m * 16 + l15][lk * 8]);
        #pragma unroll
        for (int g = 0; g < 4; ++g)
          acc[g] = __builtin_amdgcn_mfma_f32_16x16x32_bf16(a, bw[g][0],
                     (f32x4){0.f, 0.f, 0.f, 0.f}, 0, 0, 0);
      }
      #pragma unroll
      for (int kt = 1; kt < KT; ++kt) {
        const bf16x8 a = __builtin_bit_cast(bf16x8,
            *(const uint4*)&hb[p][m * 16 + l15][kt * 32 + lk * 8]);
        #pragma unroll
        for (int g = 0; g < 4; ++g)
          acc[g] = __builtin_amdgcn_mfma_f32_16x16x32_bf16(a, bw[g][kt], acc[g], 0, 0, 0);
      }
      #pragma unroll
      for (int j = 0; j < 4; ++j) {        // 5 exp + 3 rcp
        const float ei = __expf(-acc[0][j]);
        const float ef = __expf(-acc[1][j]);
        const float eg = __expf(2.f * acc[2][j]);
        const float eo = __expf(-acc[3][j]);
        const float c  = cst[m][j] * __builtin_amdgcn_rcpf(1.f + ef)
                       + (eg - 1.f) * __builtin_amdgcn_rcpf((1.f + ei) * (eg + 1.f));
        cst[m][j] = c;
        const float ec = __expf(2.f * c);
        hst[m][j] = (ec - 1.f) * __builtin_amdgcn_rcpf((1.f + eo) * (ec + 1.f));
      }
      #pragma unroll
      for (int j = 0; j < 4; ++j)
        hb[p ^ 1][m * 16 + lk * 4 + j][wv * 16 + l15] = f2bf(hst[m][j]);
    }
    if (t < SEQ - 1 && tid < BN) {         // stage x_{t+1} (L1-resident re-read)
      const float4 xv = *(const float4*)&x[(size_t)(b0 + tid) * 60 + (t + 1) * 4];
      *(unsigned int*)&hb[p ^ 1][tid][128]     = (unsigned)f2bf(xv.x) | ((unsigned)f2bf(xv.y) << 16);
      *(unsigned int*)&hb[p ^ 1][tid][128 + 2] = (unsigned)f2bf(xv.z) | ((unsigned)f2bf(xv.w) << 16);
    }
    __syncthreads();
    p ^= 1;
  }

  // ================= decoder setup =================
  #pragma unroll
  for (int m = 0; m < 4; ++m) cst[m] = hst[m];   // dec c0 = h_enc (exact f32)
  load_weights(dWih, dWhh, dbih, dbhh, oW, ob, true, wv, l15, lk, bw);
  for (int i = tid; i < 4 * HD; i += NTHR) ow_l[i >> 7][i & 127] = oW[i];
  if (tid < 4) ob_l[tid] = ob[tid];
  __syncthreads();

  {                                         // x-slot = x14 - proj(h_enc)
    float s = 0.f;
    #pragma unroll
    for (int c = 0; c < 8; ++c) {
      const int k = pq * 64 + ((c + pb) & 7) * 8;
      const uint4 hv = *(const uint4*)&hb[p][pb][k];
      const float* w = &ow_l[pd][k];
      s += bfl(hv.x) * w[0] + bfh(hv.x) * w[1]
         + bfl(hv.y) * w[2] + bfh(hv.y) * w[3]
         + bfl(hv.z) * w[4] + bfh(hv.z) * w[5]
         + bfl(hv.w) * w[6] + bfh(hv.w) * w[7];
    }
    s += __shfl_xor(s, 1);
    s += ob_l[pd];
    if (pq == 0) {
      const float x14 = x[(size_t)(b0 + pb) * 60 + 56 + pd];
      hb[p][pb][128 + pd] = f2bf(x14 - s);
    }
  }
  __syncthreads();

  // ================= decoder (folded feedback) =================
  #pragma unroll 1
  for (int t = 0; t < SEQ; ++t) {
    #pragma unroll
    for (int m = 0; m < 4; ++m) {
      f32x4 acc[4];
      {
        const bf16x8 a = __builtin_bit_cast(bf16x8,
            *(const uint4*)&hb[p][m * 16 + l15][lk * 8]);
        #pragma unroll
        for (int g = 0; g < 4; ++g)
          acc[g] = __builtin_amdgcn_mfma_f32_16x16x32_bf16(a, bw[g][0],
                     (f32x4){0.f, 0.f, 0.f, 0.f}, 0, 0, 0);
      }
      #pragma unroll
      for (int kt = 1; kt < KT; ++kt) {
        const bf16x8 a = __builtin_bit_cast(bf16x8,
            *(const uint4*)&hb[p][m * 16 + l15][kt * 32 + lk * 8]);
        #pragma unroll
        for (int g = 0; g < 4; ++g)
          acc[g] = __builtin_amdgcn_mfma_f32_16x16x32_bf16(a, bw[g][kt], acc[g], 0, 0, 0);
      }
      #pragma unroll
      for (int j = 0; j < 4; ++j) {
        const float ei = __expf(-acc[0][j]);
        const float ef = __expf(-acc[1][j]);
        const float eg = __expf(2.f * acc[2][j]);
        const float eo = __expf(-acc[3][j]);
        const float c  = cst[m][j] * __builtin_amdgcn_rcpf(1.f + ef)
                       + (eg - 1.f) * __builtin_amdgcn_rcpf((1.f + ei) * (eg + 1.f));
        cst[m][j] = c;
        const float ec = __expf(2.f * c);
        hst[m][j] = (ec - 1.f) * __builtin_amdgcn_rcpf((1.f + eo) * (ec + 1.f));
      }
      #pragma unroll
      for (int j = 0; j < 4; ++j)
        hb[p ^ 1][m * 16 + lk * 4 + j][wv * 16 + l15] = f2bf(hst[m][j]);
    }
    if (t > 0) {                            // pred[t-1] = proj(h_t); overlaps this step's work
      float s = 0.f;
      #pragma unroll
      for (int c = 0; c < 8; ++c) {
        const int k = pq * 64 + ((c + pb) & 7) * 8;
        const uint4 hv = *(const uint4*)&hb[p][pb][k];
        const float* w = &ow_l[pd][k];
        s += bfl(hv.x) * w[0] + bfh(hv.x) * w[1]
           + bfl(hv.y) * w[2] + bfh(hv.y) * w[3]
           + bfl(hv.z) * w[4] + bfh(hv.z) * w[5]
           + bfl(hv.w) * w[6] + bfh(hv.w) * w[7];
      }
      s += __shfl_xor(s, 1);
      if (pq == 0) obuf[pb][(t - 1) * 4 + pd] = s + ob_l[pd];
    }
    if (t < 2 && tid < BN)                  // zero x-slots of both buffers once
      *(uint2*)&hb[p ^ 1][tid][128] = (uint2){0u, 0u};
    __syncthreads();
    p ^= 1;
  }
  {                                         // pred[14] = proj(h_15)
    float s = 0.f;
    #pragma unroll
    for (int c = 0; c < 8; ++c) {
      const int k = pq * 64 + ((c + pb) & 7) * 8;
      const uint4 hv = *(const uint4*)&hb[p][pb][k];
      const float* w = &ow_l[pd][k];
      s += bfl(hv.x) * w[0] + bfh(hv.x) * w[1]
         + bfl(hv.y) * w[2] + bfh(hv.y) * w[3]
         + bfl(hv.z) * w[4] + bfh(hv.z) * w[5]
         + bfl(hv.w) * w[6] + bfh(hv.w) * w[7];
    }
    s += __shfl_xor(s, 1);
    if (pq == 0) obuf[pb][56 + pd] = s + ob_l[pd];
  }
  __syncthreads();

  for (int i = tid; i < BN * 15; i += NTHR) {   // coalesced dump
    const int b = i / 15, c = i % 15;
    const float4 v = *(const float4*)&obuf[b][c * 4];
    *(float4*)&out[(size_t)(b0 + b) * 60 + c * 4] = v;
  }
}

extern "C" void kernel_launch(void* const* d_in, const int* in_sizes, int n_in,
                              void* d_out, int out_size, void* d_ws, size_t ws_size,
                              hipStream_t stream) {
  const float* x    = (const float*)d_in[0];
  const float* eWih = (const float*)d_in[1];
  const float* eWhh = (const float*)d_in[2];
  const float* ebih = (const float*)d_in[3];
  const float* ebhh = (const float*)d_in[4];
  const float* dWih = (const float*)d_in[5];
  const float* dWhh = (const float*)d_in[6];
  const float* dbih = (const float*)d_in[7];
  const float* dbhh = (const float*)d_in[8];
  const float* oW   = (const float*)d_in[9];
  const float* ob   = (const float*)d_in[10];

  const int batch = in_sizes[0] / (SEQ * 4);   // 32768
  dim3 grid(batch / BN), block(NTHR);
  lstm_encdec_kernel<<<grid, block, 0, stream>>>(
      x, eWih, eWhh, ebih, ebhh, dWih, dWhh, dbih, dbhh, oW, ob, (float*)d_out);
}